// Round 5
// baseline (3061.188 us; speedup 1.0000x reference)
//
#include <hip/hip_runtime.h>

// Problem constants
#define T36   36
#define NPAR  161
#define MM    50
#define NN    4096
#define NCOLS (NN*MM)      // 204800
#define CB    32           // columns per block
#define KS1   5            // GEMM1 k-chunks (slots 0..159 = atoms 1..160)
#define YPITCH 192         // halves per Y row (24 chunks of 8; 384B = 0 mod 128B)
#define VPITCH 64          // halves per V row (8 chunks; 128B)

typedef _Float16 half8 __attribute__((ext_vector_type(8)));
typedef _Float16 half4 __attribute__((ext_vector_type(4)));
typedef float    f32x4 __attribute__((ext_vector_type(4)));

#define MFMA16(a,b,c) __builtin_amdgcn_mfma_f32_16x16x32_f16(a,b,c,0,0,0)

// D~ [t 0..47][slot 0..159] (slot s = atom s+1); rows 36..47 zero.
__device__ float g_D[48*160];
// DT~ [slot][k 0..63]: k<36 = D[k][atom(slot)], k==48 = DtD[atom(slot)][0], else 0.
__device__ float g_DT[160*64];
__device__ float g_sc[3];     // [Linv, lambda*Linv, d0]

// XOR chunk swizzle: chunk (8 halves = 16B) index u -> u ^ (c&7).
__device__ __forceinline__ int offY(int c, int h) {
  return c*YPITCH + ((((h>>3) ^ (c&7))<<3) | (h&7));
}
__device__ __forceinline__ int offV(int c, int h) {
  return c*VPITCH + ((((h>>3) ^ (c&7))<<3) | (h&7));
}

// ---------------------------------------------------------------------------
// Setup: build normalized dictionary, spectral norm L via 36x36 Gram matrix
// power iteration (validated rounds 1-2), publish slot-space D~/DT~ + scalars.
// ---------------------------------------------------------------------------
__global__ __launch_bounds__(256) void setup_kernel(const float* __restrict__ r,
                                                    const float* __restrict__ th) {
  __shared__ float Dl[T36][176];    // cols 0..160 used, 161..175 zero
  __shared__ float El[T36][T36];
  __shared__ float Fl[T36][T36];
  __shared__ float Gl[T36][T36];
  __shared__ float vl[T36], v2[T36], v3[T36];
  __shared__ float sc;
  __shared__ int jmaxs;
  const int tid = threadIdx.x;

  for (int e = tid; e < T36*176; e += 256) (&Dl[0][0])[e] = 0.0f;
  __syncthreads();

  if (tid < NPAR) {
    const int p = tid;
    float col[T36];
    if (p == 0) {
      #pragma unroll
      for (int t = 0; t < T36; ++t) col[t] = 1.0f;   // 1+1e-10 rounds to 1.0f
    } else if (p <= 80) {
      const float a = r[p-1], w = th[p-1];
      for (int t = 0; t < T36; ++t) col[t] = powf(a, (float)t) * cosf((float)t * w);
    } else {
      const float a = r[p-81], w = th[p-81];
      for (int t = 0; t < T36; ++t) col[t] = powf(a, (float)t) * sinf((float)t * w);
    }
    float s = 0.0f;
    for (int t = 0; t < T36; ++t) s += col[t]*col[t];
    const float inv = 1.0f / sqrtf(s);
    for (int t = 0; t < T36; ++t) Dl[t][p] = col[t] * inv;
  }
  __syncthreads();

  // publish slot-space D~ and DT~
  for (int e = tid; e < 48*160; e += 256) {
    const int t = e / 160, s = e % 160;
    g_D[e] = (t < T36) ? Dl[t][s+1] : 0.0f;
  }
  for (int e = tid; e < 160*64; e += 256) {
    const int p = e / 64, t = e % 64;
    float v = 0.0f;
    if (t < T36) v = Dl[t][p+1];
    else if (t == 48) {
      float s = 0.0f;
      for (int tt = 0; tt < T36; ++tt) s += Dl[tt][p+1] * Dl[tt][0];
      v = s;
    }
    g_DT[e] = v;
  }

  // E = D D^T (36x36; same nonzero spectrum as DtD)
  for (int e = tid; e < T36*T36; e += 256) {
    const int a = e / T36, b = e % T36;
    float s = 0.0f;
    for (int p = 0; p < 176; ++p) s += Dl[a][p]*Dl[b][p];
    El[a][b] = s; Fl[a][b] = s;
  }

  for (int it = 0; it < 25; ++it) {
    __syncthreads();
    for (int e = tid; e < T36*T36; e += 256) {
      const int a = e / T36, b = e % T36;
      float s = 0.0f;
      for (int k = 0; k < T36; ++k) s += Fl[a][k]*Fl[k][b];
      Gl[a][b] = s;
    }
    __syncthreads();
    if (tid == 0) {
      float tr = 0.0f;
      for (int i = 0; i < T36; ++i) tr += Gl[i][i];
      sc = 1.0f / tr;
    }
    __syncthreads();
    for (int e = tid; e < T36*T36; e += 256) {
      const int a = e / T36, b = e % T36;
      Fl[a][b] = Gl[a][b] * sc;
    }
  }
  __syncthreads();

  if (tid == 0) {
    int jm = 0; float bm = Fl[0][0];
    for (int i = 1; i < T36; ++i) if (Fl[i][i] > bm) { bm = Fl[i][i]; jm = i; }
    jmaxs = jm;
  }
  __syncthreads();
  if (tid < T36) vl[tid] = Fl[tid][jmaxs];
  __syncthreads();
  if (tid < T36) { float s = 0.0f; for (int k = 0; k < T36; ++k) s += El[tid][k]*vl[k]; v2[tid] = s; }
  __syncthreads();
  if (tid < T36) { float s = 0.0f; for (int k = 0; k < T36; ++k) s += El[tid][k]*v2[k]; v3[tid] = s; }
  __syncthreads();
  if (tid == 0) {
    float num = 0.0f, den = 0.0f;
    for (int t = 0; t < T36; ++t) { num += v3[t]*v2[t]; den += v2[t]*v2[t]; }
    const float L = num / den;
    g_sc[0] = 1.0f / L;
    g_sc[1] = 0.005f / L;
    g_sc[2] = Dl[0][0];          // d0 = 1/6 (all entries of column 0 equal)
  }
}

// ---------------------------------------------------------------------------
// FISTA, factored A = I - (DT(D.))/L, f16 split 3-product MFMA, slot-packed K.
// Atom-0 accounting (option B, consistent): LDS V = D~ x y_slots ONLY (no
// rank-1). Atom-0's contribution to u enters exclusively via virtual V-row
// 48 = y0 against DT~ column 48 = DtD[.][0]; and u0 = d0*sum_t V(t) + y0
// (exact: 36*d0^2 = 1). Epilogue Y_pred adds d0*x0 at output time.
// All LDS arrays XOR-chunk-swizzled, conflict-free pitches.
// ---------------------------------------------------------------------------
__global__ __launch_bounds__(256, 2) void fista_kernel(const float* __restrict__ y,
                                                       float* __restrict__ out) {
  __shared__ __align__(16) _Float16 Yh[CB*YPITCH];   // 12 KB
  __shared__ __align__(16) _Float16 Yl[CB*YPITCH];   // 12 KB
  __shared__ __align__(16) _Float16 Vh[CB*VPITCH];   //  4 KB
  __shared__ __align__(16) _Float16 Vl[CB*VPITCH];   //  4 KB
  __shared__ float y0f[CB];

  const int tid = threadIdx.x;
  const int w = tid >> 6;          // wave 0..3
  const int l = tid & 63;
  const int g = l >> 4;            // k-group 0..3
  const int q = l & 15;            // row/col-in-tile
  const int g0 = blockIdx.x * CB;

  const float Linv = g_sc[0];
  const float wl   = g_sc[1];
  const float d0   = g_sc[2];

  const int tbase = (w < 2) ? w*3 : 6 + (w-2)*2;   // GEMM2 tile base per wave
  const int ntile = (w < 2) ? 3 : 2;               // tiles per wave {3,3,2,2}
  const bool w3own = (w == 3) && (l < CB);         // atom-0 owner lanes
  const int oc = l;                                // owned column (wave-3)

  // ---- D~ fragments (A-operand layout: lane holds row w*16+q, k ks*32+g*8+j)
  half8 d1h[KS1], d1l[KS1];
  if (w < 3) {
    #pragma unroll
    for (int ks = 0; ks < KS1; ++ks) {
      const float* src = &g_D[(w*16 + q)*160 + ks*32 + g*8];
      #pragma unroll
      for (int j = 0; j < 8; ++j) {
        const float x = src[j];
        const _Float16 h = (_Float16)x;
        d1h[ks][j] = h;
        d1l[ks][j] = (_Float16)(x - (float)h);
      }
    }
  }
  // DT~ fragments: lane holds row (tbase+pi)*16+q, k ks*32+g*8+j
  half8 d2h[3][2], d2l[3][2];
  #pragma unroll
  for (int pi = 0; pi < 3; ++pi) {
    if (pi < ntile) {
      #pragma unroll
      for (int ks = 0; ks < 2; ++ks) {
        const float* src = &g_DT[((tbase + pi)*16 + q)*64 + ks*32 + g*8];
        #pragma unroll
        for (int j = 0; j < 8; ++j) {
          const float x = src[j];
          const _Float16 h = (_Float16)x;
          d2h[pi][ks][j] = h;
          d2l[pi][ks][j] = (_Float16)(x - (float)h);
        }
      }
    }
  }

  // ---- zero LDS state ----
  for (int e = tid; e < CB*YPITCH; e += 256) { Yh[e] = (_Float16)0.0f; Yl[e] = (_Float16)0.0f; }
  for (int e = tid; e < CB*VPITCH; e += 256) { Vh[e] = (_Float16)0.0f; Vl[e] = (_Float16)0.0f; }
  __syncthreads();

  // ---- stage Y0 (36 x 32) into V arrays, swizzled hi/lo ----
  for (int e = tid; e < CB*T36; e += 256) {
    const int c = e / T36, t = e % T36;
    const int gc = g0 + c;
    const int n = gc / 50, m = gc - n*50;
    const float x = y[(size_t)n*1800 + t*50 + m];
    const _Float16 h = (_Float16)x;
    Vh[offV(c, t)] = h;
    Vl[offV(c, t)] = (_Float16)(x - (float)h);
  }
  __syncthreads();

  // ---- cv = Linv * DT~ x Y0 (GEMM2 path; V row 48 is still zero -> exact) --
  float cv[3][2][4], xo[3][2][4], yr[3][2][4];
  float cv0 = 0.0f, xo0 = 0.0f, yr0 = 0.0f;
  {
    f32x4 acc[3][2];
    #pragma unroll
    for (int pi = 0; pi < 3; ++pi)
      #pragma unroll
      for (int ct = 0; ct < 2; ++ct) acc[pi][ct] = (f32x4){0.f,0.f,0.f,0.f};
    #pragma unroll
    for (int ks = 0; ks < 2; ++ks) {
      half8 bh[2], bl[2];
      #pragma unroll
      for (int ct = 0; ct < 2; ++ct) {
        bh[ct] = *reinterpret_cast<const half8*>(&Vh[offV(ct*16 + q, ks*32 + g*8)]);
        bl[ct] = *reinterpret_cast<const half8*>(&Vl[offV(ct*16 + q, ks*32 + g*8)]);
      }
      #pragma unroll
      for (int pi = 0; pi < 3; ++pi) {
        if (pi < ntile) {
          #pragma unroll
          for (int ct = 0; ct < 2; ++ct) {
            acc[pi][ct] = MFMA16(d2h[pi][ks], bh[ct], acc[pi][ct]);
            acc[pi][ct] = MFMA16(d2h[pi][ks], bl[ct], acc[pi][ct]);
            acc[pi][ct] = MFMA16(d2l[pi][ks], bh[ct], acc[pi][ct]);
          }
        }
      }
    }
    #pragma unroll
    for (int pi = 0; pi < 3; ++pi)
      #pragma unroll
      for (int ct = 0; ct < 2; ++ct)
        #pragma unroll
        for (int i = 0; i < 4; ++i) cv[pi][ct][i] = acc[pi][ct][i] * Linv;
    if (w3own) {   // cv0 = Linv * d0 * sum_t Y0[t][oc]
      float s = 0.0f;
      #pragma unroll
      for (int u = 0; u < 5; ++u) {   // halves 0..39; 36..39 are zero
        const half8 h8 = *reinterpret_cast<const half8*>(&Vh[offV(oc, u*8)]);
        const half8 l8 = *reinterpret_cast<const half8*>(&Vl[offV(oc, u*8)]);
        #pragma unroll
        for (int j = 0; j < 8; ++j) s += (float)h8[j] + (float)l8[j];
      }
      cv0 = Linv * d0 * s;
    }
  }

  // ---- pre-loop step 1: x1 = shrink(cv), y2 = x1 (tt = 0) ----
  #pragma unroll
  for (int pi = 0; pi < 3; ++pi) {
    if (pi < ntile) {
      #pragma unroll
      for (int ct = 0; ct < 2; ++ct) {
        half4 yh4, yl4;
        #pragma unroll
        for (int i = 0; i < 4; ++i) {
          const float gq = cv[pi][ct][i];
          const float xn = fmaxf(0.0f, gq - wl) + fminf(0.0f, gq + wl);
          xo[pi][ct][i] = xn;
          yr[pi][ct][i] = xn;
          const _Float16 h = (_Float16)xn;
          yh4[i] = h;
          yl4[i] = (_Float16)(xn - (float)h);
        }
        const int p0 = (tbase + pi)*16 + g*4;
        *reinterpret_cast<half4*>(&Yh[offY(ct*16 + q, p0)]) = yh4;
        *reinterpret_cast<half4*>(&Yl[offY(ct*16 + q, p0)]) = yl4;
      }
    }
  }
  if (w3own) {
    const float xn = fmaxf(0.0f, cv0 - wl) + fminf(0.0f, cv0 + wl);
    xo0 = xn; yr0 = xn;
  }

  // ---- FISTA main loop: iterations 2..100 (99 iters) ----
  float tk = 1.61803398875f;    // t_2
  for (int it = 1; it < 100; ++it) {
    __syncthreads();   // B1: Y-state visible; V free

    if (w < 3) {
      // GEMM1: V = D~ x Y (slots only; atom-0 handled via virtual row 48)
      f32x4 a1[2] = {(f32x4){0.f,0.f,0.f,0.f}, (f32x4){0.f,0.f,0.f,0.f}};
      #pragma unroll
      for (int ks = 0; ks < KS1; ++ks) {
        half8 bh[2], bl[2];
        #pragma unroll
        for (int ct = 0; ct < 2; ++ct) {
          bh[ct] = *reinterpret_cast<const half8*>(&Yh[offY(ct*16 + q, ks*32 + g*8)]);
          bl[ct] = *reinterpret_cast<const half8*>(&Yl[offY(ct*16 + q, ks*32 + g*8)]);
        }
        #pragma unroll
        for (int ct = 0; ct < 2; ++ct) {
          a1[ct] = MFMA16(d1h[ks], bh[ct], a1[ct]);
          a1[ct] = MFMA16(d1h[ks], bl[ct], a1[ct]);
          a1[ct] = MFMA16(d1l[ks], bh[ct], a1[ct]);
        }
      }
      #pragma unroll
      for (int ct = 0; ct < 2; ++ct) {
        half4 h4, l4;
        #pragma unroll
        for (int i = 0; i < 4; ++i) {
          const float v = a1[ct][i];
          const _Float16 h = (_Float16)v;
          h4[i] = h;
          l4[i] = (_Float16)(v - (float)h);
        }
        *reinterpret_cast<half4*>(&Vh[offV(ct*16 + q, w*16 + g*4)]) = h4;
        *reinterpret_cast<half4*>(&Vl[offV(ct*16 + q, w*16 + g*4)]) = l4;
      }
    } else if (w3own) {
      // virtual V row 48 = y0 (consumed by DT~ column 48 = DtD[.][0])
      const _Float16 h = (_Float16)yr0;
      Vh[offV(oc, 48)] = h;
      Vl[offV(oc, 48)] = (_Float16)(yr0 - (float)h);
    }
    __syncthreads();   // B2: V visible

    // GEMM2: u = DT~ x V
    f32x4 acc[3][2];
    #pragma unroll
    for (int pi = 0; pi < 3; ++pi)
      #pragma unroll
      for (int ct = 0; ct < 2; ++ct) acc[pi][ct] = (f32x4){0.f,0.f,0.f,0.f};
    #pragma unroll
    for (int ks = 0; ks < 2; ++ks) {
      half8 bh[2], bl[2];
      #pragma unroll
      for (int ct = 0; ct < 2; ++ct) {
        bh[ct] = *reinterpret_cast<const half8*>(&Vh[offV(ct*16 + q, ks*32 + g*8)]);
        bl[ct] = *reinterpret_cast<const half8*>(&Vl[offV(ct*16 + q, ks*32 + g*8)]);
      }
      #pragma unroll
      for (int pi = 0; pi < 3; ++pi) {
        if (pi < ntile) {
          #pragma unroll
          for (int ct = 0; ct < 2; ++ct) {
            acc[pi][ct] = MFMA16(d2h[pi][ks], bh[ct], acc[pi][ct]);
            acc[pi][ct] = MFMA16(d2h[pi][ks], bl[ct], acc[pi][ct]);
            acc[pi][ct] = MFMA16(d2l[pi][ks], bh[ct], acc[pi][ct]);
          }
        }
      }
    }
    float u0 = 0.0f;
    if (w3own) {   // u0 = d0 * sum_{t<36} V[t][oc] + y0  (36*d0^2 = 1)
      float s = 0.0f;
      #pragma unroll
      for (int u = 0; u < 5; ++u) {
        const half8 h8 = *reinterpret_cast<const half8*>(&Vh[offV(oc, u*8)]);
        const half8 l8 = *reinterpret_cast<const half8*>(&Vl[offV(oc, u*8)]);
        #pragma unroll
        for (int j = 0; j < 8; ++j) s += (float)h8[j] + (float)l8[j];
      }
      u0 = d0 * s + yr0;
    }

    const float tnew = 0.5f*(1.0f + sqrtf(fmaf(4.0f*tk, tk, 1.0f)));
    const float tt   = (tk - 1.0f) / tnew;
    tk = tnew;

    // elementwise update + write new y-state
    #pragma unroll
    for (int pi = 0; pi < 3; ++pi) {
      if (pi < ntile) {
        #pragma unroll
        for (int ct = 0; ct < 2; ++ct) {
          half4 yh4, yl4;
          #pragma unroll
          for (int i = 0; i < 4; ++i) {
            const float gq = fmaf(-Linv, acc[pi][ct][i], yr[pi][ct][i]) + cv[pi][ct][i];
            const float xn = fmaxf(0.0f, gq - wl) + fminf(0.0f, gq + wl);
            const float yn = fmaf(tt, xn - xo[pi][ct][i], xn);
            xo[pi][ct][i] = xn;
            yr[pi][ct][i] = yn;
            const _Float16 h = (_Float16)yn;
            yh4[i] = h;
            yl4[i] = (_Float16)(yn - (float)h);
          }
          const int p0 = (tbase + pi)*16 + g*4;
          *reinterpret_cast<half4*>(&Yh[offY(ct*16 + q, p0)]) = yh4;
          *reinterpret_cast<half4*>(&Yl[offY(ct*16 + q, p0)]) = yl4;
        }
      }
    }
    if (w3own) {
      const float gq = fmaf(-Linv, u0, yr0) + cv0;
      const float xn = fmaxf(0.0f, gq - wl) + fminf(0.0f, gq + wl);
      const float yn = fmaf(tt, xn - xo0, xn);
      xo0 = xn; yr0 = yn;
    }
  }

  // ---- epilogue ----
  const size_t YP = (size_t)NN * T36 * MM;   // Y_pred element count

  // C_pred: atoms 1..160 from slot lanes, atom 0 from owners
  #pragma unroll
  for (int pi = 0; pi < 3; ++pi) {
    if (pi < ntile) {
      #pragma unroll
      for (int ct = 0; ct < 2; ++ct)
        #pragma unroll
        for (int i = 0; i < 4; ++i) {
          const int atom = (tbase + pi)*16 + g*4 + i + 1;
          const int gc = g0 + ct*16 + q;
          const int n = gc / 50, m = gc - n*50;
          out[YP + (size_t)n*(NPAR*MM) + (size_t)atom*MM + m] = xo[pi][ct][i];
        }
    }
  }
  if (w3own) {
    const int gc = g0 + oc;
    const int n = gc / 50, m = gc - n*50;
    out[YP + (size_t)n*(NPAR*MM) + m] = xo0;    // atom 0
  }

  // write x_final into Y-state (+ x0 into y0f) and rerun GEMM1 for Y_pred
  #pragma unroll
  for (int pi = 0; pi < 3; ++pi) {
    if (pi < ntile) {
      #pragma unroll
      for (int ct = 0; ct < 2; ++ct) {
        half4 xh4, xl4;
        #pragma unroll
        for (int i = 0; i < 4; ++i) {
          const float v = xo[pi][ct][i];
          const _Float16 h = (_Float16)v;
          xh4[i] = h;
          xl4[i] = (_Float16)(v - (float)h);
        }
        const int p0 = (tbase + pi)*16 + g*4;
        *reinterpret_cast<half4*>(&Yh[offY(ct*16 + q, p0)]) = xh4;
        *reinterpret_cast<half4*>(&Yl[offY(ct*16 + q, p0)]) = xl4;
      }
    }
  }
  if (w3own) y0f[oc] = xo0;
  __syncthreads();

  if (w < 3) {
    f32x4 a1[2] = {(f32x4){0.f,0.f,0.f,0.f}, (f32x4){0.f,0.f,0.f,0.f}};
    #pragma unroll
    for (int ks = 0; ks < KS1; ++ks) {
      half8 bh[2], bl[2];
      #pragma unroll
      for (int ct = 0; ct < 2; ++ct) {
        bh[ct] = *reinterpret_cast<const half8*>(&Yh[offY(ct*16 + q, ks*32 + g*8)]);
        bl[ct] = *reinterpret_cast<const half8*>(&Yl[offY(ct*16 + q, ks*32 + g*8)]);
      }
      #pragma unroll
      for (int ct = 0; ct < 2; ++ct) {
        a1[ct] = MFMA16(d1h[ks], bh[ct], a1[ct]);
        a1[ct] = MFMA16(d1h[ks], bl[ct], a1[ct]);
        a1[ct] = MFMA16(d1l[ks], bh[ct], a1[ct]);
      }
    }
    #pragma unroll
    for (int ct = 0; ct < 2; ++ct) {
      const float r1 = d0 * y0f[ct*16 + q];   // rank-1 d0*x0 added at output
      #pragma unroll
      for (int i = 0; i < 4; ++i) {
        const int t = w*16 + g*4 + i;
        if (t < T36) {
          const int gc = g0 + ct*16 + q;
          const int n = gc / 50, m = gc - n*50;
          out[(size_t)n*1800 + t*50 + m] = a1[ct][i] + r1;
        }
      }
    }
  }
}

extern "C" void kernel_launch(void* const* d_in, const int* in_sizes, int n_in,
                              void* d_out, int out_size, void* d_ws, size_t ws_size,
                              hipStream_t stream) {
  const float* y  = (const float*)d_in[0];
  const float* r  = (const float*)d_in[1];
  const float* th = (const float*)d_in[2];
  float* out = (float*)d_out;
  (void)d_ws; (void)ws_size; (void)in_sizes; (void)n_in; (void)out_size;

  setup_kernel<<<1, 256, 0, stream>>>(r, th);
  fista_kernel<<<NCOLS / CB, 256, 0, stream>>>(y, out);
}